// Round 10
// baseline (191.352 us; speedup 1.0000x reference)
//
#include <hip/hip_runtime.h>
#include <cstddef>

#define S_LEN 4096
#define C_DIM 256
#define NHEADS 8
#define HDIM 32

typedef __attribute__((ext_vector_type(8))) _Float16 half8;
typedef __attribute__((ext_vector_type(4))) _Float16 half4;
typedef __attribute__((ext_vector_type(2))) _Float16 h2t;
typedef __attribute__((ext_vector_type(2))) __fp16 fp16x2;
typedef __attribute__((ext_vector_type(4))) float floatx4;

// scale * log2(e) folded into W_q and bias_q at prep time
#define SC2F ((float)(0.17677669529663687 * 1.4426950408889634))

// ---------------------------------------------------------------- prep + GN stats (fused)
__global__ __launch_bounds__(256) void prep_stats(
    const float* __restrict__ qkv_w, const float* __restrict__ proj_w,
    const float* __restrict__ qkv_b, const float* __restrict__ x,
    _Float16* __restrict__ wq, _Float16* __restrict__ wp,
    float* __restrict__ qbias, float* __restrict__ gstat)
{
  const int blk = blockIdx.x;
  const int tid = threadIdx.x;
  if (blk < 64) {
    __shared__ float red[2][4];
    const int g = blk & 31, b = blk >> 5;
    const float* xb = x + ((size_t)b * C_DIM + g * 8) * S_LEN;
    const float4* x4 = (const float4*)xb;
    float sum = 0.f, sumsq = 0.f;
    for (int i = tid; i < 8192; i += 256) {
      float4 v = x4[i];
      sum += v.x + v.y + v.z + v.w;
      sumsq += v.x * v.x + v.y * v.y + v.z * v.z + v.w * v.w;
    }
    for (int off = 1; off < 64; off <<= 1) {
      sum += __shfl_xor(sum, off, 64);
      sumsq += __shfl_xor(sumsq, off, 64);
    }
    const int wv = tid >> 6, lane = tid & 63;
    if (lane == 0) { red[0][wv] = sum; red[1][wv] = sumsq; }
    __syncthreads();
    if (tid == 0) {
      float s = red[0][0] + red[0][1] + red[0][2] + red[0][3];
      float sq = red[1][0] + red[1][1] + red[1][2] + red[1][3];
      float mean = s * (1.f / 32768.f);
      float var = sq * (1.f / 32768.f) - mean * mean;
      gstat[((size_t)b * 32 + g) * 2 + 0] = mean;
      gstat[((size_t)b * 32 + g) * 2 + 1] = rsqrtf(var + 1e-6f);
    }
  } else {
    int idx = (blk - 64) * 256 + tid;
    if (idx < 768 * 256) {
      float v = qkv_w[idx];
      if (idx < 256 * 256) v *= SC2F;          // q rows
      wq[idx] = (_Float16)v;
    } else if (idx < 768 * 256 + 256 * 256) {
      int i = idx - 768 * 256;
      wp[i] = (_Float16)proj_w[i];
    } else if (idx < 768 * 256 + 256 * 256 + 768) {
      int i = idx - (768 * 256 + 256 * 256);
      float bv = qkv_b[i];
      if (i < 256) bv *= SC2F;
      qbias[i] = bv;
    }
  }
}

// ---------------------------------------------------------------- QKV GEMM + inline GN
__global__ __launch_bounds__(256) void qkv_gn_gemm(
    const _Float16* __restrict__ W, const float* __restrict__ bias,
    const float* __restrict__ x, const float* __restrict__ gamma,
    const float* __restrict__ beta, const float* __restrict__ gstat,
    _Float16* __restrict__ qo, _Float16* __restrict__ ko_,
    _Float16* __restrict__ vo)
{
  __shared__ __align__(16) _Float16 Ld[64 * 264];   // [s][c], stride 264
  const int tid = threadIdx.x;
  const int b = blockIdx.z;
  const int s0 = blockIdx.y * 64;

  {  // ---- inline GN apply: x (c,s) -> Ld[s][c] f16
    const int c0 = (tid & 127) * 2, c1 = c0 + 1;
    const int sh = tid >> 7;                         // s-half 0/1
    const int g = c0 >> 3;
    const float mean = gstat[((size_t)b * 32 + g) * 2 + 0];
    const float rstd = gstat[((size_t)b * 32 + g) * 2 + 1];
    const float ga0 = gamma[c0] * rstd, be0 = beta[c0] - mean * ga0;
    const float ga1 = gamma[c1] * rstd, be1 = beta[c1] - mean * ga1;
    const float4* xa = (const float4*)(x + ((size_t)b * C_DIM + c0) * S_LEN + s0 + sh * 32);
    const float4* xc = (const float4*)(x + ((size_t)b * C_DIM + c1) * S_LEN + s0 + sh * 32);
    #pragma unroll
    for (int j = 0; j < 8; ++j) {
      float4 a = xa[j], c = xc[j];
      int sl = sh * 32 + j * 4;
      *(h2t*)&Ld[(sl + 0) * 264 + c0] = (h2t){ (_Float16)(a.x * ga0 + be0), (_Float16)(c.x * ga1 + be1) };
      *(h2t*)&Ld[(sl + 1) * 264 + c0] = (h2t){ (_Float16)(a.y * ga0 + be0), (_Float16)(c.y * ga1 + be1) };
      *(h2t*)&Ld[(sl + 2) * 264 + c0] = (h2t){ (_Float16)(a.z * ga0 + be0), (_Float16)(c.z * ga1 + be1) };
      *(h2t*)&Ld[(sl + 3) * 264 + c0] = (h2t){ (_Float16)(a.w * ga0 + be0), (_Float16)(c.w * ga1 + be1) };
    }
  }
  __syncthreads();

  const int lane = tid & 63, wv = tid >> 6;
  const int m = lane & 15, quad = lane >> 4;
  const int mtb = blockIdx.x * 8 + wv * 2;      // 2 mt tiles per wave
  const _Float16* wrow0 = W + (size_t)((mtb + 0) * 16 + m) * C_DIM + quad * 8;
  const _Float16* wrow1 = W + (size_t)((mtb + 1) * 16 + m) * C_DIM + quad * 8;
  const _Float16* lp = &Ld[m * 264 + quad * 8];

  floatx4 acc[2][4];
  #pragma unroll
  for (int j = 0; j < 2; ++j)
    #pragma unroll
    for (int s = 0; s < 4; ++s) acc[j][s] = (floatx4){0.f,0.f,0.f,0.f};

  #pragma unroll
  for (int k0 = 0; k0 < C_DIM; k0 += 32) {
    half8 b0 = *(const half8*)(lp + k0);
    half8 b1 = *(const half8*)(lp + 16 * 264 + k0);
    half8 b2 = *(const half8*)(lp + 32 * 264 + k0);
    half8 b3 = *(const half8*)(lp + 48 * 264 + k0);
    half8 a0 = *(const half8*)(wrow0 + k0);
    half8 a1 = *(const half8*)(wrow1 + k0);
    acc[0][0] = __builtin_amdgcn_mfma_f32_16x16x32_f16(a0, b0, acc[0][0], 0, 0, 0);
    acc[0][1] = __builtin_amdgcn_mfma_f32_16x16x32_f16(a0, b1, acc[0][1], 0, 0, 0);
    acc[0][2] = __builtin_amdgcn_mfma_f32_16x16x32_f16(a0, b2, acc[0][2], 0, 0, 0);
    acc[0][3] = __builtin_amdgcn_mfma_f32_16x16x32_f16(a0, b3, acc[0][3], 0, 0, 0);
    acc[1][0] = __builtin_amdgcn_mfma_f32_16x16x32_f16(a1, b0, acc[1][0], 0, 0, 0);
    acc[1][1] = __builtin_amdgcn_mfma_f32_16x16x32_f16(a1, b1, acc[1][1], 0, 0, 0);
    acc[1][2] = __builtin_amdgcn_mfma_f32_16x16x32_f16(a1, b2, acc[1][2], 0, 0, 0);
    acc[1][3] = __builtin_amdgcn_mfma_f32_16x16x32_f16(a1, b3, acc[1][3], 0, 0, 0);
  }

  #pragma unroll
  for (int j = 0; j < 2; ++j) {
    const int ob = (mtb + j) * 16 + quad * 4;
    const float bv0 = bias[ob], bv1 = bias[ob + 1],
                bv2 = bias[ob + 2], bv3 = bias[ob + 3];
    #pragma unroll
    for (int sub = 0; sub < 4; ++sub) {
      int s = s0 + sub * 16 + m;
      float v0 = acc[j][sub][0] + bv0, v1 = acc[j][sub][1] + bv1,
            v2 = acc[j][sub][2] + bv2, v3 = acc[j][sub][3] + bv3;
      if (ob < 512) {                       // q or k: (B,NH,S,hd)
        _Float16* dst = (ob < 256) ? qo : ko_;
        int oo = ob & 255, n = oo >> 5, d0 = oo & 31;
        half4 h = { (_Float16)v0, (_Float16)v1, (_Float16)v2, (_Float16)v3 };
        *(half4*)(dst + (((size_t)b * NHEADS + n) * S_LEN + s) * HDIM + d0) = h;
      } else {                              // v: (B,NH,hd,S)
        int oo = ob - 512, n = oo >> 5, d0 = oo & 31;
        _Float16* dst = vo + ((size_t)b * NHEADS + n) * HDIM * S_LEN + s;
        dst[(size_t)(d0 + 0) * S_LEN] = (_Float16)v0;
        dst[(size_t)(d0 + 1) * S_LEN] = (_Float16)v1;
        dst[(size_t)(d0 + 2) * S_LEN] = (_Float16)v2;
        dst[(size_t)(d0 + 3) * S_LEN] = (_Float16)v3;
      }
    }
  }
}

// ---------------------------------------------------------------- Attention
// Barrier-free main loop: 4 waves/block, each wave owns a private 32-key
// slice of every 128-key tile; Q (128 rows) lives in registers (8 B-frags).
// K A-frags and V A-frags load DIRECTLY from global (coalesced); no LDS, no
// __syncthreads until the final 3-round merge tree over the 4 key slices.
// Writes unnormalized partials (po f16, pl f32); proj_gemm merges kh halves.
__global__ __launch_bounds__(256) void attn_kernel(
    const _Float16* __restrict__ q, const _Float16* __restrict__ k,
    const _Float16* __restrict__ v, _Float16* __restrict__ po,
    float* __restrict__ pl)
{
  __shared__ unsigned int Ml[2][64][41];             // merge slots, ~21 KB
  const int tid = threadIdx.x;
  const int lane = tid & 63, wv = tid >> 6;          // wv 0..3
  const int m = lane & 15, quad = lane >> 4;
  const int n = blockIdx.y, b = blockIdx.z;
  const int qc = blockIdx.x >> 1, kh = blockIdx.x & 1;
  const int q0 = qc * 128;
  const int bh = b * NHEADS + n;

  const _Float16* qb = q + (size_t)bh * S_LEN * HDIM;
  const _Float16* kb = k + (size_t)bh * S_LEN * HDIM + (size_t)kh * 2048 * HDIM;
  const _Float16* vb = v + (size_t)bh * HDIM * S_LEN + (size_t)kh * 2048;

  // Q B-frags (register-resident): qf[j] covers q rows q0+j*16..+15
  half8 qf[8];
  #pragma unroll
  for (int j = 0; j < 8; ++j)
    qf[j] = *(const half8*)(qb + (size_t)(q0 + j * 16 + m) * HDIM + quad * 8);

  // wave's key slice within each 128-key tile: [wv*32, wv*32+32)
  const _Float16* kp0 = kb + (size_t)(wv * 32 + m) * HDIM + quad * 8;
  const _Float16* kp1 = kp0 + 16 * HDIM;
  const _Float16* vp00 = vb + (size_t)m * S_LEN + wv * 32 + quad * 4;       // d 0-15, kk 0-15
  const _Float16* vp01 = vp00 + 16;                                         // d 0-15, kk 16-31
  const _Float16* vp10 = vp00 + (size_t)16 * S_LEN;                         // d 16-31
  const _Float16* vp11 = vp10 + 16;

  int4 kr0 = *(const int4*)kp0, kr1 = *(const int4*)kp1;
  int2 v00 = *(const int2*)vp00, v01 = *(const int2*)vp01;
  int2 v10 = *(const int2*)vp10, v11 = *(const int2*)vp11;

  floatx4 o[8][2];
  float l[8];
  #pragma unroll
  for (int j = 0; j < 8; ++j) {
    o[j][0] = (floatx4){0.f,0.f,0.f,0.f};
    o[j][1] = (floatx4){0.f,0.f,0.f,0.f};
    l[j] = 0.f;
  }
  const fp16x2 one2 = { (__fp16)1.0f, (__fp16)1.0f };

  for (int it = 0; it < 16; ++it) {                  // 16 x 128 keys = 2048
    half8 kf0 = __builtin_bit_cast(half8, kr0);
    half8 kf1 = __builtin_bit_cast(half8, kr1);
    half4 vf00 = __builtin_bit_cast(half4, v00);
    half4 vf01 = __builtin_bit_cast(half4, v01);
    half4 vf10 = __builtin_bit_cast(half4, v10);
    half4 vf11 = __builtin_bit_cast(half4, v11);
    kp0 += 128 * HDIM; kp1 += 128 * HDIM;
    vp00 += 128; vp01 += 128; vp10 += 128; vp11 += 128;
    kr0 = *(const int4*)kp0; kr1 = *(const int4*)kp1;   // prefetch next tile
    v00 = *(const int2*)vp00; v01 = *(const int2*)vp01;
    v10 = *(const int2*)vp10; v11 = *(const int2*)vp11;
    #pragma unroll
    for (int j = 0; j < 8; ++j) {
      floatx4 z = {0.f,0.f,0.f,0.f};
      floatx4 s0 = __builtin_amdgcn_mfma_f32_16x16x32_f16(kf0, qf[j], z, 0, 0, 0);
      floatx4 s1 = __builtin_amdgcn_mfma_f32_16x16x32_f16(kf1, qf[j], z, 0, 0, 0);
      float e0 = __builtin_amdgcn_exp2f(s0[0]);
      float e1 = __builtin_amdgcn_exp2f(s0[1]);
      float e2 = __builtin_amdgcn_exp2f(s0[2]);
      float e3 = __builtin_amdgcn_exp2f(s0[3]);
      float f0 = __builtin_amdgcn_exp2f(s1[0]);
      float f1 = __builtin_amdgcn_exp2f(s1[1]);
      float f2 = __builtin_amdgcn_exp2f(s1[2]);
      float f3 = __builtin_amdgcn_exp2f(s1[3]);
      half4 p0, p1;
      fp16x2 p0lo = __builtin_amdgcn_cvt_pkrtz(e0, e1);
      fp16x2 p0hi = __builtin_amdgcn_cvt_pkrtz(e2, e3);
      fp16x2 p1lo = __builtin_amdgcn_cvt_pkrtz(f0, f1);
      fp16x2 p1hi = __builtin_amdgcn_cvt_pkrtz(f2, f3);
      *(fp16x2*)&p0 = p0lo; *((fp16x2*)&p0 + 1) = p0hi;
      *(fp16x2*)&p1 = p1lo; *((fp16x2*)&p1 + 1) = p1hi;
      float lj = l[j];
      lj = __builtin_amdgcn_fdot2(p0lo, one2, lj, false);
      lj = __builtin_amdgcn_fdot2(p0hi, one2, lj, false);
      lj = __builtin_amdgcn_fdot2(p1lo, one2, lj, false);
      lj = __builtin_amdgcn_fdot2(p1hi, one2, lj, false);
      l[j] = lj;
      o[j][0] = __builtin_amdgcn_mfma_f32_16x16x16f16(vf00, p0, o[j][0], 0, 0, 0);
      o[j][1] = __builtin_amdgcn_mfma_f32_16x16x16f16(vf10, p0, o[j][1], 0, 0, 0);
      o[j][0] = __builtin_amdgcn_mfma_f32_16x16x16f16(vf01, p1, o[j][0], 0, 0, 0);
      o[j][1] = __builtin_amdgcn_mfma_f32_16x16x16f16(vf11, p1, o[j][1], 0, 0, 0);
    }
  }

  // ---- merge tree across the 4 key-slice waves (payload: o as f16, l f32)
  // round 1: waves 2,3 write; waves 0,1 add. round 2: wave 1 writes; 0 adds.
  #define WRITE_SLOT(s)                                                      \
    { unsigned int* d_ = &Ml[s][lane][0];                                    \
      _Pragma("unroll") for (int j = 0; j < 8; ++j) {                        \
        half4 h0_ = { (_Float16)o[j][0][0], (_Float16)o[j][0][1],            \
                      (_Float16)o[j][0][2], (_Float16)o[j][0][3] };          \
        half4 h1_ = { (_Float16)o[j][1][0], (_Float16)o[j][1][1],            \
                      (_Float16)o[j][1][2], (_Float16)o[j][1][3] };          \
        int2 a_ = __builtin_bit_cast(int2, h0_);                             \
        int2 b_ = __builtin_bit_cast(int2, h1_);                             \
        d_[j*4+0] = a_.x; d_[j*4+1] = a_.y;                                  \
        d_[j*4+2] = b_.x; d_[j*4+3] = b_.y; }                                \
      _Pragma("unroll") for (int j = 0; j < 8; ++j)                          \
        d_[32+j] = __builtin_bit_cast(unsigned int, l[j]); }
  #define ADD_SLOT(s)                                                        \
    { const unsigned int* r_ = &Ml[s][lane][0];                              \
      _Pragma("unroll") for (int j = 0; j < 8; ++j) {                        \
        int2 a_ = { (int)r_[j*4+0], (int)r_[j*4+1] };                        \
        int2 b_ = { (int)r_[j*4+2], (int)r_[j*4+3] };                        \
        half4 h0_ = __builtin_bit_cast(half4, a_);                           \
        half4 h1_ = __builtin_bit_cast(half4, b_);                           \
        _Pragma("unroll") for (int r2 = 0; r2 < 4; ++r2) {                   \
          o[j][0][r2] += (float)h0_[r2];                                     \
          o[j][1][r2] += (float)h1_[r2]; } }                                 \
      _Pragma("unroll") for (int j = 0; j < 8; ++j)                          \
        l[j] += __builtin_bit_cast(float, r_[32+j]); }

  if (wv >= 2) WRITE_SLOT(wv - 2);
  __syncthreads();
  if (wv < 2) ADD_SLOT(wv);
  __syncthreads();
  if (wv == 1) WRITE_SLOT(0);
  __syncthreads();
  if (wv == 0) {
    ADD_SLOT(0);
    _Float16* pob = po + (size_t)kh * 2097152 + ((size_t)bh * S_LEN) * HDIM;
    #pragma unroll
    for (int j = 0; j < 8; ++j) {
      float lj = l[j];
      lj += __shfl_xor(lj, 16, 64);
      lj += __shfl_xor(lj, 32, 64);
      int qrow = q0 + j * 16 + m;
      half4 h0 = { (_Float16)o[j][0][0], (_Float16)o[j][0][1],
                   (_Float16)o[j][0][2], (_Float16)o[j][0][3] };
      half4 h1 = { (_Float16)o[j][1][0], (_Float16)o[j][1][1],
                   (_Float16)o[j][1][2], (_Float16)o[j][1][3] };
      _Float16* poh = pob + (size_t)qrow * HDIM;
      *(half4*)(poh + quad * 4) = h0;
      *(half4*)(poh + 16 + quad * 4) = h1;
      if (quad == 0) pl[(size_t)kh * 65536 + (size_t)bh * S_LEN + qrow] = lj;
    }
  }
}

// ---------------------------------------------------------------- Proj GEMM (+ fused merge)
__global__ __launch_bounds__(256) void proj_gemm(
    const _Float16* __restrict__ W, const float* __restrict__ bias,
    const _Float16* __restrict__ po, const float* __restrict__ pl,
    const float* __restrict__ x, float* __restrict__ out)
{
  const int tid = threadIdx.x;
  const int lane = tid & 63, wv = tid >> 6;
  const int m = lane & 15, quad = lane >> 4;
  const int mt = blockIdx.x * 4 + wv;  // 0..15
  const int s0 = blockIdx.y * 64;
  const int b = blockIdx.z;
  const int row = mt * 16 + m;

  float inv[8][4];
  #pragma unroll
  for (int n = 0; n < 8; ++n) {
    #pragma unroll
    for (int sub = 0; sub < 4; ++sub) {
      size_t idx = ((size_t)(b * NHEADS + n)) * S_LEN + s0 + sub * 16 + m;
      inv[n][sub] = 1.f / (pl[idx] + pl[65536 + idx]);
    }
  }

  const _Float16* wrow = W + (size_t)row * C_DIM + quad * 8;
  floatx4 acc0 = {0.f,0.f,0.f,0.f}, acc1 = acc0, acc2 = acc0, acc3 = acc0;
  #pragma unroll
  for (int k0 = 0; k0 < C_DIM; k0 += 32) {
    const int n = k0 >> 5;
    const int d0 = quad * 8;
    half8 bf[4];
    #pragma unroll
    for (int sub = 0; sub < 4; ++sub) {
      size_t idx = (((size_t)(b * NHEADS + n)) * S_LEN + s0 + sub * 16 + m) * HDIM + d0;
      half8 a = *(const half8*)(po + idx);
      half8 c = *(const half8*)(po + 2097152 + idx);
      _Float16 iv = (_Float16)inv[n][sub];
      bf[sub] = (a + c) * iv;
    }
    half8 af = *(const half8*)(wrow + k0);
    acc0 = __builtin_amdgcn_mfma_f32_16x16x32_f16(af, bf[0], acc0, 0, 0, 0);
    acc1 = __builtin_amdgcn_mfma_f32_16x16x32_f16(af, bf[1], acc1, 0, 0, 0);
    acc2 = __builtin_amdgcn_mfma_f32_16x16x32_f16(af, bf[2], acc2, 0, 0, 0);
    acc3 = __builtin_amdgcn_mfma_f32_16x16x32_f16(af, bf[3], acc3, 0, 0, 0);
  }
  floatx4 accs[4] = {acc0, acc1, acc2, acc3};
  #pragma unroll
  for (int sub = 0; sub < 4; ++sub) {
    int s = s0 + sub * 16 + m;
    #pragma unroll
    for (int r = 0; r < 4; ++r) {
      int c = mt * 16 + quad * 4 + r;
      size_t idx = ((size_t)b * C_DIM + c) * S_LEN + s;
      out[idx] = x[idx] + accs[sub][r] + bias[c];
    }
  }
}

// ---------------------------------------------------------------- launch
extern "C" void kernel_launch(void* const* d_in, const int* in_sizes, int n_in,
                              void* d_out, int out_size, void* d_ws, size_t ws_size,
                              hipStream_t stream) {
  const float* x        = (const float*)d_in[0];
  const float* gn_gamma = (const float*)d_in[1];
  const float* gn_beta  = (const float*)d_in[2];
  const float* qkv_w    = (const float*)d_in[3];
  const float* qkv_b    = (const float*)d_in[4];
  const float* proj_w   = (const float*)d_in[5];
  const float* proj_b   = (const float*)d_in[6];
  float* out = (float*)d_out;

  const size_t n1 = (size_t)2 * S_LEN * C_DIM;   // 2M elems = 4 MB f16
  char* ws = (char*)d_ws;
  _Float16* qx  = (_Float16*)ws;                 // (B,NH,S,hd)
  _Float16* kx  = qx + n1;                       // (B,NH,S,hd)
  _Float16* vx  = kx + n1;                       // (B,NH,hd,S)
  _Float16* wq  = vx + n1;                       // 768x256 f16
  _Float16* wp  = wq + 768 * 256;                // 256x256 f16
  float*    qbias = (float*)(wp + 256 * 256);    // 768 f32
  float*    gstat = qbias + 768;                 // 128 f32
  _Float16* po  = (_Float16*)(gstat + 128);      // 2 x 2M f16 = 8 MB
  float*    pl  = (float*)(po + 2 * n1);         // 2 x 64K f32 = 512 KB

  prep_stats<<<1091, 256, 0, stream>>>(qkv_w, proj_w, qkv_b, x, wq, wp, qbias, gstat);
  qkv_gn_gemm<<<dim3(6, 64, 2), 256, 0, stream>>>(wq, qbias, x, gn_gamma, gn_beta, gstat, qx, kx, vx);
  attn_kernel<<<dim3(64, 8, 2), 256, 0, stream>>>(qx, kx, vx, po, pl);
  proj_gemm<<<dim3(4, 64, 2), 256, 0, stream>>>(wp, proj_b, po, pl, x, out);
}

// Round 11
// 156.234 us; speedup vs baseline: 1.2248x; 1.2248x over previous
//
#include <hip/hip_runtime.h>
#include <cstddef>

#define S_LEN 4096
#define C_DIM 256
#define NHEADS 8
#define HDIM 32

typedef __attribute__((ext_vector_type(8))) _Float16 half8;
typedef __attribute__((ext_vector_type(4))) _Float16 half4;
typedef __attribute__((ext_vector_type(2))) _Float16 h2t;
typedef __attribute__((ext_vector_type(2))) __fp16 fp16x2;
typedef __attribute__((ext_vector_type(4))) float floatx4;

// scale * log2(e) folded into W_q and bias_q at prep time
#define SC2F ((float)(0.17677669529663687 * 1.4426950408889634))

// ---------------------------------------------------------------- prep + GN partial stats
// blocks 0..511: per-eighth partial sums of each (g,b) group -> pstat[gb][e][2]
// blocks 512..1538: weight fp32->f16 conversion
__global__ __launch_bounds__(256) void prep_stats(
    const float* __restrict__ qkv_w, const float* __restrict__ proj_w,
    const float* __restrict__ qkv_b, const float* __restrict__ x,
    _Float16* __restrict__ wq, _Float16* __restrict__ wp,
    float* __restrict__ qbias, float* __restrict__ pstat)
{
  const int blk = blockIdx.x;
  const int tid = threadIdx.x;
  if (blk < 512) {
    __shared__ float red[2][4];
    const int gb = blk >> 3, e = blk & 7;       // gb = b*32+g
    const int g = gb & 31, b = gb >> 5;
    const float* xb = x + ((size_t)b * C_DIM + g * 8) * S_LEN + e * 4096;
    const float4* x4 = (const float4*)xb;       // 1024 float4
    float sum = 0.f, sumsq = 0.f;
    #pragma unroll
    for (int i = 0; i < 4; ++i) {
      float4 v = x4[tid + i * 256];
      sum += v.x + v.y + v.z + v.w;
      sumsq += v.x * v.x + v.y * v.y + v.z * v.z + v.w * v.w;
    }
    for (int off = 1; off < 64; off <<= 1) {
      sum += __shfl_xor(sum, off, 64);
      sumsq += __shfl_xor(sumsq, off, 64);
    }
    const int wv = tid >> 6, lane = tid & 63;
    if (lane == 0) { red[0][wv] = sum; red[1][wv] = sumsq; }
    __syncthreads();
    if (tid == 0) {
      pstat[(gb * 8 + e) * 2 + 0] = red[0][0] + red[0][1] + red[0][2] + red[0][3];
      pstat[(gb * 8 + e) * 2 + 1] = red[1][0] + red[1][1] + red[1][2] + red[1][3];
    }
  } else {
    int idx = (blk - 512) * 256 + tid;
    if (idx < 768 * 256) {
      float v = qkv_w[idx];
      if (idx < 256 * 256) v *= SC2F;          // q rows
      wq[idx] = (_Float16)v;
    } else if (idx < 768 * 256 + 256 * 256) {
      int i = idx - 768 * 256;
      wp[i] = (_Float16)proj_w[i];
    } else if (idx < 768 * 256 + 256 * 256 + 768) {
      int i = idx - (768 * 256 + 256 * 256);
      float bv = qkv_b[i];
      if (i < 256) bv *= SC2F;
      qbias[i] = bv;
    }
  }
}

// ---------------------------------------------------------------- QKV GEMM + inline GN
// Reduces the 8 per-group partials inline (L1-hot), then GN+transpose to LDS
// and the 2-mt-per-wave MFMA K-loop (R8 structure).
__global__ __launch_bounds__(256) void qkv_gn_gemm(
    const _Float16* __restrict__ W, const float* __restrict__ bias,
    const float* __restrict__ x, const float* __restrict__ gamma,
    const float* __restrict__ beta, const float* __restrict__ pstat,
    _Float16* __restrict__ qo, _Float16* __restrict__ ko_,
    _Float16* __restrict__ vo)
{
  __shared__ __align__(16) _Float16 Ld[64 * 264];   // [s][c], stride 264
  const int tid = threadIdx.x;
  const int b = blockIdx.z;
  const int s0 = blockIdx.y * 64;

  {  // ---- inline GN apply: x (c,s) -> Ld[s][c] f16
    const int c0 = (tid & 127) * 2, c1 = c0 + 1;
    const int sh = tid >> 7;                         // s-half 0/1
    const int g = c0 >> 3;
    const int gb = b * 32 + g;
    float s = 0.f, sq = 0.f;
    #pragma unroll
    for (int e = 0; e < 8; ++e) {
      s  += pstat[(gb * 8 + e) * 2 + 0];
      sq += pstat[(gb * 8 + e) * 2 + 1];
    }
    const float mean = s * (1.f / 32768.f);
    const float rstd = rsqrtf(sq * (1.f / 32768.f) - mean * mean + 1e-6f);
    const float ga0 = gamma[c0] * rstd, be0 = beta[c0] - mean * ga0;
    const float ga1 = gamma[c1] * rstd, be1 = beta[c1] - mean * ga1;
    const float4* xa = (const float4*)(x + ((size_t)b * C_DIM + c0) * S_LEN + s0 + sh * 32);
    const float4* xc = (const float4*)(x + ((size_t)b * C_DIM + c1) * S_LEN + s0 + sh * 32);
    #pragma unroll
    for (int j = 0; j < 8; ++j) {
      float4 a = xa[j], c = xc[j];
      int sl = sh * 32 + j * 4;
      *(h2t*)&Ld[(sl + 0) * 264 + c0] = (h2t){ (_Float16)(a.x * ga0 + be0), (_Float16)(c.x * ga1 + be1) };
      *(h2t*)&Ld[(sl + 1) * 264 + c0] = (h2t){ (_Float16)(a.y * ga0 + be0), (_Float16)(c.y * ga1 + be1) };
      *(h2t*)&Ld[(sl + 2) * 264 + c0] = (h2t){ (_Float16)(a.z * ga0 + be0), (_Float16)(c.z * ga1 + be1) };
      *(h2t*)&Ld[(sl + 3) * 264 + c0] = (h2t){ (_Float16)(a.w * ga0 + be0), (_Float16)(c.w * ga1 + be1) };
    }
  }
  __syncthreads();

  const int lane = tid & 63, wv = tid >> 6;
  const int m = lane & 15, quad = lane >> 4;
  const int mtb = blockIdx.x * 8 + wv * 2;      // 2 mt tiles per wave
  const _Float16* wrow0 = W + (size_t)((mtb + 0) * 16 + m) * C_DIM + quad * 8;
  const _Float16* wrow1 = W + (size_t)((mtb + 1) * 16 + m) * C_DIM + quad * 8;
  const _Float16* lp = &Ld[m * 264 + quad * 8];

  floatx4 acc[2][4];
  #pragma unroll
  for (int j = 0; j < 2; ++j)
    #pragma unroll
    for (int s = 0; s < 4; ++s) acc[j][s] = (floatx4){0.f,0.f,0.f,0.f};

  #pragma unroll
  for (int k0 = 0; k0 < C_DIM; k0 += 32) {
    half8 b0 = *(const half8*)(lp + k0);
    half8 b1 = *(const half8*)(lp + 16 * 264 + k0);
    half8 b2 = *(const half8*)(lp + 32 * 264 + k0);
    half8 b3 = *(const half8*)(lp + 48 * 264 + k0);
    half8 a0 = *(const half8*)(wrow0 + k0);
    half8 a1 = *(const half8*)(wrow1 + k0);
    acc[0][0] = __builtin_amdgcn_mfma_f32_16x16x32_f16(a0, b0, acc[0][0], 0, 0, 0);
    acc[0][1] = __builtin_amdgcn_mfma_f32_16x16x32_f16(a0, b1, acc[0][1], 0, 0, 0);
    acc[0][2] = __builtin_amdgcn_mfma_f32_16x16x32_f16(a0, b2, acc[0][2], 0, 0, 0);
    acc[0][3] = __builtin_amdgcn_mfma_f32_16x16x32_f16(a0, b3, acc[0][3], 0, 0, 0);
    acc[1][0] = __builtin_amdgcn_mfma_f32_16x16x32_f16(a1, b0, acc[1][0], 0, 0, 0);
    acc[1][1] = __builtin_amdgcn_mfma_f32_16x16x32_f16(a1, b1, acc[1][1], 0, 0, 0);
    acc[1][2] = __builtin_amdgcn_mfma_f32_16x16x32_f16(a1, b2, acc[1][2], 0, 0, 0);
    acc[1][3] = __builtin_amdgcn_mfma_f32_16x16x32_f16(a1, b3, acc[1][3], 0, 0, 0);
  }

  #pragma unroll
  for (int j = 0; j < 2; ++j) {
    const int ob = (mtb + j) * 16 + quad * 4;
    const float bv0 = bias[ob], bv1 = bias[ob + 1],
                bv2 = bias[ob + 2], bv3 = bias[ob + 3];
    #pragma unroll
    for (int sub = 0; sub < 4; ++sub) {
      int s = s0 + sub * 16 + m;
      float v0 = acc[j][sub][0] + bv0, v1 = acc[j][sub][1] + bv1,
            v2 = acc[j][sub][2] + bv2, v3 = acc[j][sub][3] + bv3;
      if (ob < 512) {                       // q or k: (B,NH,S,hd)
        _Float16* dst = (ob < 256) ? qo : ko_;
        int oo = ob & 255, n = oo >> 5, d0 = oo & 31;
        half4 h = { (_Float16)v0, (_Float16)v1, (_Float16)v2, (_Float16)v3 };
        *(half4*)(dst + (((size_t)b * NHEADS + n) * S_LEN + s) * HDIM + d0) = h;
      } else {                              // v: (B,NH,hd,S)
        int oo = ob - 512, n = oo >> 5, d0 = oo & 31;
        _Float16* dst = vo + ((size_t)b * NHEADS + n) * HDIM * S_LEN + s;
        dst[(size_t)(d0 + 0) * S_LEN] = (_Float16)v0;
        dst[(size_t)(d0 + 1) * S_LEN] = (_Float16)v1;
        dst[(size_t)(d0 + 2) * S_LEN] = (_Float16)v2;
        dst[(size_t)(d0 + 3) * S_LEN] = (_Float16)v3;
      }
    }
  }
}

// ---------------------------------------------------------------- Attention (R8 structure)
// 8 waves, 16 q/wave, 2-way key split (2048 keys/block), 64-key LDS tiles,
// int2 staging, double-buffered. Unnormalized partials (po f16, pl f32).
__global__ __launch_bounds__(512) void attn_kernel(
    const _Float16* __restrict__ q, const _Float16* __restrict__ k,
    const _Float16* __restrict__ v, _Float16* __restrict__ po,
    float* __restrict__ pl)
{
  __shared__ __align__(16) _Float16 Kl[2][64 * 40];  // (kk, d) stride 40
  __shared__ __align__(16) _Float16 Vl[2][32 * 68];  // (d, kk) stride 68
  const int tid = threadIdx.x;
  const int lane = tid & 63, wv = tid >> 6;          // wv 0..7
  const int m = lane & 15, quad = lane >> 4;
  const int n = blockIdx.y, b = blockIdx.z;
  const int qc = blockIdx.x >> 1, kh = blockIdx.x & 1;
  const int q0 = qc * 128 + wv * 16;
  const int bh = b * NHEADS + n;

  const _Float16* qb = q + (size_t)bh * S_LEN * HDIM;
  const _Float16* kb = k + (size_t)bh * S_LEN * HDIM + (size_t)kh * 2048 * HDIM;
  const _Float16* vb = v + (size_t)bh * HDIM * S_LEN + (size_t)kh * 2048;

  // Q B-frag (QK): lane q=m holds d=quad*8+j
  half8 qf = *(const half8*)(qb + (size_t)(q0 + m) * HDIM + quad * 8);

  // staging: wave wv stages K rows [wv*8,+8), V rows [wv*4,+4); 8B per lane
  const int krow = wv * 8 + (lane >> 3), kc = (lane & 7) * 4;
  const int vrow = wv * 4 + (lane >> 4), vc = (lane & 15) * 4;
  const _Float16* kg = kb + (size_t)krow * HDIM + kc;
  const _Float16* vg = vb + (size_t)vrow * S_LEN + vc;
  const int klds = krow * 40 + kc;
  const int vlds = vrow * 68 + vc;

  int2 kreg = *(const int2*)kg;
  int2 vreg = *(const int2*)vg;
  const _Float16* kgp = kg + 64 * HDIM;
  const _Float16* vgp = vg + 64;

  floatx4 o0 = {0.f,0.f,0.f,0.f}, o1 = o0;   // d-tiles 0/1 for this wave's 16 q
  float l0 = 0.f;
  const fp16x2 one2 = { (__fp16)1.0f, (__fp16)1.0f };

  #pragma unroll 2
  for (int it = 0; it < 32; ++it) {          // 32 x 64 keys = 2048 (half)
    const int bufi = it & 1;
    *(int2*)(&Kl[bufi][klds]) = kreg;
    *(int2*)(&Vl[bufi][vlds]) = vreg;
    kreg = *(const int2*)kgp; kgp += 64 * HDIM;   // unconditional prefetch
    vreg = *(const int2*)vgp; vgp += 64;
    __syncthreads();
    const _Float16* Kb = Kl[bufi];
    const _Float16* Vb = Vl[bufi];
    #pragma unroll
    for (int t = 0; t < 4; ++t) {
      half8 kf = *(const half8*)(Kb + (t * 16 + m) * 40 + quad * 8);
      half4 vf0 = *(const half4*)(Vb + m * 68 + t * 16 + quad * 4);
      half4 vf1 = *(const half4*)(Vb + (16 + m) * 68 + t * 16 + quad * 4);
      floatx4 z = {0.f,0.f,0.f,0.f};
      floatx4 s0 = __builtin_amdgcn_mfma_f32_16x16x32_f16(kf, qf, z, 0, 0, 0);
      float e0 = __builtin_amdgcn_exp2f(s0[0]);
      float e1 = __builtin_amdgcn_exp2f(s0[1]);
      float e2 = __builtin_amdgcn_exp2f(s0[2]);
      float e3 = __builtin_amdgcn_exp2f(s0[3]);
      half4 p0;
      fp16x2 plo = __builtin_amdgcn_cvt_pkrtz(e0, e1);
      fp16x2 phi = __builtin_amdgcn_cvt_pkrtz(e2, e3);
      *(fp16x2*)&p0 = plo;
      *((fp16x2*)&p0 + 1) = phi;
      l0 = __builtin_amdgcn_fdot2(plo, one2, l0, false);
      l0 = __builtin_amdgcn_fdot2(phi, one2, l0, false);
      o0 = __builtin_amdgcn_mfma_f32_16x16x16f16(vf0, p0, o0, 0, 0, 0);
      o1 = __builtin_amdgcn_mfma_f32_16x16x16f16(vf1, p0, o1, 0, 0, 0);
    }
  }
  // l split across 4 quads (keys) -> reduce
  l0 += __shfl_xor(l0, 16, 64);
  l0 += __shfl_xor(l0, 32, 64);
  // partial store (unnormalized): po[kh][bh][q][d] f16, pl[kh][bh*4096+q]
  _Float16* poh = po + (size_t)kh * 2097152 + ((size_t)bh * S_LEN + q0 + m) * HDIM;
  half4 h0 = { (_Float16)o0[0], (_Float16)o0[1], (_Float16)o0[2], (_Float16)o0[3] };
  half4 h1 = { (_Float16)o1[0], (_Float16)o1[1], (_Float16)o1[2], (_Float16)o1[3] };
  *(half4*)(poh + quad * 4) = h0;
  *(half4*)(poh + 16 + quad * 4) = h1;
  if (quad == 0) pl[(size_t)kh * 65536 + (size_t)bh * S_LEN + q0 + m] = l0;
}

// ---------------------------------------------------------------- Proj GEMM (+ fused merge)
__global__ __launch_bounds__(256) void proj_gemm(
    const _Float16* __restrict__ W, const float* __restrict__ bias,
    const _Float16* __restrict__ po, const float* __restrict__ pl,
    const float* __restrict__ x, float* __restrict__ out)
{
  const int tid = threadIdx.x;
  const int lane = tid & 63, wv = tid >> 6;
  const int m = lane & 15, quad = lane >> 4;
  const int mt = blockIdx.x * 4 + wv;  // 0..15
  const int s0 = blockIdx.y * 64;
  const int b = blockIdx.z;
  const int row = mt * 16 + m;

  float inv[8][4];
  #pragma unroll
  for (int n = 0; n < 8; ++n) {
    #pragma unroll
    for (int sub = 0; sub < 4; ++sub) {
      size_t idx = ((size_t)(b * NHEADS + n)) * S_LEN + s0 + sub * 16 + m;
      inv[n][sub] = 1.f / (pl[idx] + pl[65536 + idx]);
    }
  }

  const _Float16* wrow = W + (size_t)row * C_DIM + quad * 8;
  floatx4 acc0 = {0.f,0.f,0.f,0.f}, acc1 = acc0, acc2 = acc0, acc3 = acc0;
  #pragma unroll
  for (int k0 = 0; k0 < C_DIM; k0 += 32) {
    const int n = k0 >> 5;
    const int d0 = quad * 8;
    half8 bf[4];
    #pragma unroll
    for (int sub = 0; sub < 4; ++sub) {
      size_t idx = (((size_t)(b * NHEADS + n)) * S_LEN + s0 + sub * 16 + m) * HDIM + d0;
      half8 a = *(const half8*)(po + idx);
      half8 c = *(const half8*)(po + 2097152 + idx);
      _Float16 iv = (_Float16)inv[n][sub];
      bf[sub] = (a + c) * iv;
    }
    half8 af = *(const half8*)(wrow + k0);
    acc0 = __builtin_amdgcn_mfma_f32_16x16x32_f16(af, bf[0], acc0, 0, 0, 0);
    acc1 = __builtin_amdgcn_mfma_f32_16x16x32_f16(af, bf[1], acc1, 0, 0, 0);
    acc2 = __builtin_amdgcn_mfma_f32_16x16x32_f16(af, bf[2], acc2, 0, 0, 0);
    acc3 = __builtin_amdgcn_mfma_f32_16x16x32_f16(af, bf[3], acc3, 0, 0, 0);
  }
  floatx4 accs[4] = {acc0, acc1, acc2, acc3};
  #pragma unroll
  for (int sub = 0; sub < 4; ++sub) {
    int s = s0 + sub * 16 + m;
    #pragma unroll
    for (int r = 0; r < 4; ++r) {
      int c = mt * 16 + quad * 4 + r;
      size_t idx = ((size_t)b * C_DIM + c) * S_LEN + s;
      out[idx] = x[idx] + accs[sub][r] + bias[c];
    }
  }
}

// ---------------------------------------------------------------- launch
extern "C" void kernel_launch(void* const* d_in, const int* in_sizes, int n_in,
                              void* d_out, int out_size, void* d_ws, size_t ws_size,
                              hipStream_t stream) {
  const float* x        = (const float*)d_in[0];
  const float* gn_gamma = (const float*)d_in[1];
  const float* gn_beta  = (const float*)d_in[2];
  const float* qkv_w    = (const float*)d_in[3];
  const float* qkv_b    = (const float*)d_in[4];
  const float* proj_w   = (const float*)d_in[5];
  const float* proj_b   = (const float*)d_in[6];
  float* out = (float*)d_out;

  const size_t n1 = (size_t)2 * S_LEN * C_DIM;   // 2M elems = 4 MB f16
  char* ws = (char*)d_ws;
  _Float16* qx  = (_Float16*)ws;                 // (B,NH,S,hd)
  _Float16* kx  = qx + n1;                       // (B,NH,S,hd)
  _Float16* vx  = kx + n1;                       // (B,NH,hd,S)
  _Float16* wq  = vx + n1;                       // 768x256 f16
  _Float16* wp  = wq + 768 * 256;                // 256x256 f16
  float*    qbias = (float*)(wp + 256 * 256);    // 768 f32
  float*    pstat = qbias + 768;                 // 64*8*2 f32 = 4 KB
  _Float16* po  = (_Float16*)(pstat + 1024);     // 2 x 2M f16 = 8 MB
  float*    pl  = (float*)(po + 2 * n1);         // 2 x 64K f32 = 512 KB

  prep_stats<<<1539, 256, 0, stream>>>(qkv_w, proj_w, qkv_b, x, wq, wp, qbias, pstat);
  qkv_gn_gemm<<<dim3(6, 64, 2), 256, 0, stream>>>(wq, qbias, x, gn_gamma, gn_beta, pstat, qx, kx, vx);
  attn_kernel<<<dim3(64, 8, 2), 512, 0, stream>>>(qx, kx, vx, po, pl);
  proj_gemm<<<dim3(4, 64, 2), 256, 0, stream>>>(wp, proj_b, po, pl, x, out);
}

// Round 12
// 154.883 us; speedup vs baseline: 1.2355x; 1.0087x over previous
//
#include <hip/hip_runtime.h>
#include <cstddef>

#define S_LEN 4096
#define C_DIM 256
#define NHEADS 8
#define HDIM 32

typedef __attribute__((ext_vector_type(8))) _Float16 half8;
typedef __attribute__((ext_vector_type(4))) _Float16 half4;
typedef __attribute__((ext_vector_type(2))) _Float16 h2t;
typedef __attribute__((ext_vector_type(2))) __fp16 fp16x2;
typedef __attribute__((ext_vector_type(4))) float floatx4;

// scale * log2(e) folded into W_q and bias_q at prep time
#define SC2F ((float)(0.17677669529663687 * 1.4426950408889634))

// ---------------------------------------------------------------- prep + GN partial stats
__global__ __launch_bounds__(256) void prep_stats(
    const float* __restrict__ qkv_w, const float* __restrict__ proj_w,
    const float* __restrict__ qkv_b, const float* __restrict__ x,
    _Float16* __restrict__ wq, _Float16* __restrict__ wp,
    float* __restrict__ qbias, float* __restrict__ pstat)
{
  const int blk = blockIdx.x;
  const int tid = threadIdx.x;
  if (blk < 512) {
    __shared__ float red[2][4];
    const int gb = blk >> 3, e = blk & 7;       // gb = b*32+g
    const int g = gb & 31, b = gb >> 5;
    const float* xb = x + ((size_t)b * C_DIM + g * 8) * S_LEN + e * 4096;
    const float4* x4 = (const float4*)xb;       // 1024 float4
    float sum = 0.f, sumsq = 0.f;
    #pragma unroll
    for (int i = 0; i < 4; ++i) {
      float4 v = x4[tid + i * 256];
      sum += v.x + v.y + v.z + v.w;
      sumsq += v.x * v.x + v.y * v.y + v.z * v.z + v.w * v.w;
    }
    for (int off = 1; off < 64; off <<= 1) {
      sum += __shfl_xor(sum, off, 64);
      sumsq += __shfl_xor(sumsq, off, 64);
    }
    const int wv = tid >> 6, lane = tid & 63;
    if (lane == 0) { red[0][wv] = sum; red[1][wv] = sumsq; }
    __syncthreads();
    if (tid == 0) {
      pstat[(gb * 8 + e) * 2 + 0] = red[0][0] + red[0][1] + red[0][2] + red[0][3];
      pstat[(gb * 8 + e) * 2 + 1] = red[1][0] + red[1][1] + red[1][2] + red[1][3];
    }
  } else {
    int idx = (blk - 512) * 256 + tid;
    if (idx < 768 * 256) {
      float v = qkv_w[idx];
      if (idx < 256 * 256) v *= SC2F;          // q rows
      wq[idx] = (_Float16)v;
    } else if (idx < 768 * 256 + 256 * 256) {
      int i = idx - 768 * 256;
      wp[i] = (_Float16)proj_w[i];
    } else if (idx < 768 * 256 + 256 * 256 + 768) {
      int i = idx - (768 * 256 + 256 * 256);
      float bv = qkv_b[i];
      if (i < 256) bv *= SC2F;
      qbias[i] = bv;
    }
  }
}

// ---------------------------------------------------------------- QKV GEMM + inline GN
// R11 structure; v-epilogue (blocks bx>=4, all-v) staged through LDS for
// coalesced 16B global stores instead of strided 2B scatter.
__global__ __launch_bounds__(256) void qkv_gn_gemm(
    const _Float16* __restrict__ W, const float* __restrict__ bias,
    const float* __restrict__ x, const float* __restrict__ gamma,
    const float* __restrict__ beta, const float* __restrict__ pstat,
    _Float16* __restrict__ qo, _Float16* __restrict__ ko_,
    _Float16* __restrict__ vo)
{
  __shared__ __align__(16) _Float16 Ld[64 * 264];   // [s][c], stride 264
  const int tid = threadIdx.x;
  const int b = blockIdx.z;
  const int s0 = blockIdx.y * 64;

  {  // ---- inline GN apply: x (c,s) -> Ld[s][c] f16
    const int c0 = (tid & 127) * 2, c1 = c0 + 1;
    const int sh = tid >> 7;                         // s-half 0/1
    const int g = c0 >> 3;
    const int gb = b * 32 + g;
    float s = 0.f, sq = 0.f;
    #pragma unroll
    for (int e = 0; e < 8; ++e) {
      s  += pstat[(gb * 8 + e) * 2 + 0];
      sq += pstat[(gb * 8 + e) * 2 + 1];
    }
    const float mean = s * (1.f / 32768.f);
    const float rstd = rsqrtf(sq * (1.f / 32768.f) - mean * mean + 1e-6f);
    const float ga0 = gamma[c0] * rstd, be0 = beta[c0] - mean * ga0;
    const float ga1 = gamma[c1] * rstd, be1 = beta[c1] - mean * ga1;
    const float4* xa = (const float4*)(x + ((size_t)b * C_DIM + c0) * S_LEN + s0 + sh * 32);
    const float4* xc = (const float4*)(x + ((size_t)b * C_DIM + c1) * S_LEN + s0 + sh * 32);
    #pragma unroll
    for (int j = 0; j < 8; ++j) {
      float4 a = xa[j], c = xc[j];
      int sl = sh * 32 + j * 4;
      *(h2t*)&Ld[(sl + 0) * 264 + c0] = (h2t){ (_Float16)(a.x * ga0 + be0), (_Float16)(c.x * ga1 + be1) };
      *(h2t*)&Ld[(sl + 1) * 264 + c0] = (h2t){ (_Float16)(a.y * ga0 + be0), (_Float16)(c.y * ga1 + be1) };
      *(h2t*)&Ld[(sl + 2) * 264 + c0] = (h2t){ (_Float16)(a.z * ga0 + be0), (_Float16)(c.z * ga1 + be1) };
      *(h2t*)&Ld[(sl + 3) * 264 + c0] = (h2t){ (_Float16)(a.w * ga0 + be0), (_Float16)(c.w * ga1 + be1) };
    }
  }
  __syncthreads();

  const int lane = tid & 63, wv = tid >> 6;
  const int m = lane & 15, quad = lane >> 4;
  const int mtb = blockIdx.x * 8 + wv * 2;      // 2 mt tiles per wave
  const _Float16* wrow0 = W + (size_t)((mtb + 0) * 16 + m) * C_DIM + quad * 8;
  const _Float16* wrow1 = W + (size_t)((mtb + 1) * 16 + m) * C_DIM + quad * 8;
  const _Float16* lp = &Ld[m * 264 + quad * 8];

  floatx4 acc[2][4];
  #pragma unroll
  for (int j = 0; j < 2; ++j)
    #pragma unroll
    for (int s = 0; s < 4; ++s) acc[j][s] = (floatx4){0.f,0.f,0.f,0.f};

  #pragma unroll
  for (int k0 = 0; k0 < C_DIM; k0 += 32) {
    half8 b0 = *(const half8*)(lp + k0);
    half8 b1 = *(const half8*)(lp + 16 * 264 + k0);
    half8 b2 = *(const half8*)(lp + 32 * 264 + k0);
    half8 b3 = *(const half8*)(lp + 48 * 264 + k0);
    half8 a0 = *(const half8*)(wrow0 + k0);
    half8 a1 = *(const half8*)(wrow1 + k0);
    acc[0][0] = __builtin_amdgcn_mfma_f32_16x16x32_f16(a0, b0, acc[0][0], 0, 0, 0);
    acc[0][1] = __builtin_amdgcn_mfma_f32_16x16x32_f16(a0, b1, acc[0][1], 0, 0, 0);
    acc[0][2] = __builtin_amdgcn_mfma_f32_16x16x32_f16(a0, b2, acc[0][2], 0, 0, 0);
    acc[0][3] = __builtin_amdgcn_mfma_f32_16x16x32_f16(a0, b3, acc[0][3], 0, 0, 0);
    acc[1][0] = __builtin_amdgcn_mfma_f32_16x16x32_f16(a1, b0, acc[1][0], 0, 0, 0);
    acc[1][1] = __builtin_amdgcn_mfma_f32_16x16x32_f16(a1, b1, acc[1][1], 0, 0, 0);
    acc[1][2] = __builtin_amdgcn_mfma_f32_16x16x32_f16(a1, b2, acc[1][2], 0, 0, 0);
    acc[1][3] = __builtin_amdgcn_mfma_f32_16x16x32_f16(a1, b3, acc[1][3], 0, 0, 0);
  }

  if (blockIdx.x < 4) {
    // ---- q/k epilogue: coalesced half4 stores (unchanged)
    #pragma unroll
    for (int j = 0; j < 2; ++j) {
      const int ob = (mtb + j) * 16 + quad * 4;
      const float bv0 = bias[ob], bv1 = bias[ob + 1],
                  bv2 = bias[ob + 2], bv3 = bias[ob + 3];
      #pragma unroll
      for (int sub = 0; sub < 4; ++sub) {
        int s = s0 + sub * 16 + m;
        half4 h = { (_Float16)(acc[j][sub][0] + bv0), (_Float16)(acc[j][sub][1] + bv1),
                    (_Float16)(acc[j][sub][2] + bv2), (_Float16)(acc[j][sub][3] + bv3) };
        _Float16* dst = (ob < 256) ? qo : ko_;
        int oo = ob & 255, n = oo >> 5, d0 = oo & 31;
        *(half4*)(dst + (((size_t)b * NHEADS + n) * S_LEN + s) * HDIM + d0) = h;
      }
    }
  } else {
    // ---- v epilogue via LDS: stage [128 ch][64 s] (stride 72), store 16B
    __syncthreads();                          // Ld b-frag reads complete
    _Float16* VLd = Ld;                       // reuse, 128*72*2B = 18.4 KB
    #pragma unroll
    for (int j = 0; j < 2; ++j) {
      const int ob = (mtb + j) * 16 + quad * 4;
      const int lch = (wv * 2 + j) * 16 + quad * 4;   // 0..127
      const float bv0 = bias[ob], bv1 = bias[ob + 1],
                  bv2 = bias[ob + 2], bv3 = bias[ob + 3];
      #pragma unroll
      for (int sub = 0; sub < 4; ++sub) {
        int s = sub * 16 + m;
        VLd[(lch + 0) * 72 + s] = (_Float16)(acc[j][sub][0] + bv0);
        VLd[(lch + 1) * 72 + s] = (_Float16)(acc[j][sub][1] + bv1);
        VLd[(lch + 2) * 72 + s] = (_Float16)(acc[j][sub][2] + bv2);
        VLd[(lch + 3) * 72 + s] = (_Float16)(acc[j][sub][3] + bv3);
      }
    }
    __syncthreads();
    const int lch = tid >> 1, sh = tid & 1;   // half-row per thread (32 halfs)
    const int oo = (blockIdx.x - 4) * 128 + lch;    // 0..255
    const int n = oo >> 5, d = oo & 31;
    _Float16* dst = vo + ((size_t)(b * NHEADS + n) * HDIM + d) * S_LEN + s0 + sh * 32;
    const _Float16* src = VLd + lch * 72 + sh * 32;
    *(half8*)(dst + 0)  = *(const half8*)(src + 0);
    *(half8*)(dst + 8)  = *(const half8*)(src + 8);
    *(half8*)(dst + 16) = *(const half8*)(src + 16);
    *(half8*)(dst + 24) = *(const half8*)(src + 24);
  }
}

// ---------------------------------------------------------------- Attention (R8 structure)
__global__ __launch_bounds__(512) void attn_kernel(
    const _Float16* __restrict__ q, const _Float16* __restrict__ k,
    const _Float16* __restrict__ v, _Float16* __restrict__ po,
    float* __restrict__ pl)
{
  __shared__ __align__(16) _Float16 Kl[2][64 * 40];  // (kk, d) stride 40
  __shared__ __align__(16) _Float16 Vl[2][32 * 68];  // (d, kk) stride 68
  const int tid = threadIdx.x;
  const int lane = tid & 63, wv = tid >> 6;          // wv 0..7
  const int m = lane & 15, quad = lane >> 4;
  const int n = blockIdx.y, b = blockIdx.z;
  const int qc = blockIdx.x >> 1, kh = blockIdx.x & 1;
  const int q0 = qc * 128 + wv * 16;
  const int bh = b * NHEADS + n;

  const _Float16* qb = q + (size_t)bh * S_LEN * HDIM;
  const _Float16* kb = k + (size_t)bh * S_LEN * HDIM + (size_t)kh * 2048 * HDIM;
  const _Float16* vb = v + (size_t)bh * HDIM * S_LEN + (size_t)kh * 2048;

  // Q B-frag (QK): lane q=m holds d=quad*8+j
  half8 qf = *(const half8*)(qb + (size_t)(q0 + m) * HDIM + quad * 8);

  // staging: wave wv stages K rows [wv*8,+8), V rows [wv*4,+4); 8B per lane
  const int krow = wv * 8 + (lane >> 3), kc = (lane & 7) * 4;
  const int vrow = wv * 4 + (lane >> 4), vc = (lane & 15) * 4;
  const _Float16* kg = kb + (size_t)krow * HDIM + kc;
  const _Float16* vg = vb + (size_t)vrow * S_LEN + vc;
  const int klds = krow * 40 + kc;
  const int vlds = vrow * 68 + vc;

  int2 kreg = *(const int2*)kg;
  int2 vreg = *(const int2*)vg;
  const _Float16* kgp = kg + 64 * HDIM;
  const _Float16* vgp = vg + 64;

  floatx4 o0 = {0.f,0.f,0.f,0.f}, o1 = o0;   // d-tiles 0/1 for this wave's 16 q
  float l0 = 0.f;
  const fp16x2 one2 = { (__fp16)1.0f, (__fp16)1.0f };

  #pragma unroll 2
  for (int it = 0; it < 32; ++it) {          // 32 x 64 keys = 2048 (half)
    const int bufi = it & 1;
    *(int2*)(&Kl[bufi][klds]) = kreg;
    *(int2*)(&Vl[bufi][vlds]) = vreg;
    kreg = *(const int2*)kgp; kgp += 64 * HDIM;   // unconditional prefetch
    vreg = *(const int2*)vgp; vgp += 64;
    __syncthreads();
    const _Float16* Kb = Kl[bufi];
    const _Float16* Vb = Vl[bufi];
    #pragma unroll
    for (int t = 0; t < 4; ++t) {
      half8 kf = *(const half8*)(Kb + (t * 16 + m) * 40 + quad * 8);
      half4 vf0 = *(const half4*)(Vb + m * 68 + t * 16 + quad * 4);
      half4 vf1 = *(const half4*)(Vb + (16 + m) * 68 + t * 16 + quad * 4);
      floatx4 z = {0.f,0.f,0.f,0.f};
      floatx4 s0 = __builtin_amdgcn_mfma_f32_16x16x32_f16(kf, qf, z, 0, 0, 0);
      float e0 = __builtin_amdgcn_exp2f(s0[0]);
      float e1 = __builtin_amdgcn_exp2f(s0[1]);
      float e2 = __builtin_amdgcn_exp2f(s0[2]);
      float e3 = __builtin_amdgcn_exp2f(s0[3]);
      half4 p0;
      fp16x2 plo = __builtin_amdgcn_cvt_pkrtz(e0, e1);
      fp16x2 phi = __builtin_amdgcn_cvt_pkrtz(e2, e3);
      *(fp16x2*)&p0 = plo;
      *((fp16x2*)&p0 + 1) = phi;
      l0 = __builtin_amdgcn_fdot2(plo, one2, l0, false);
      l0 = __builtin_amdgcn_fdot2(phi, one2, l0, false);
      o0 = __builtin_amdgcn_mfma_f32_16x16x16f16(vf0, p0, o0, 0, 0, 0);
      o1 = __builtin_amdgcn_mfma_f32_16x16x16f16(vf1, p0, o1, 0, 0, 0);
    }
  }
  // l split across 4 quads (keys) -> reduce
  l0 += __shfl_xor(l0, 16, 64);
  l0 += __shfl_xor(l0, 32, 64);
  // partial store (unnormalized): po[kh][bh][q][d] f16, pl[kh][bh*4096+q]
  _Float16* poh = po + (size_t)kh * 2097152 + ((size_t)bh * S_LEN + q0 + m) * HDIM;
  half4 h0 = { (_Float16)o0[0], (_Float16)o0[1], (_Float16)o0[2], (_Float16)o0[3] };
  half4 h1 = { (_Float16)o1[0], (_Float16)o1[1], (_Float16)o1[2], (_Float16)o1[3] };
  *(half4*)(poh + quad * 4) = h0;
  *(half4*)(poh + 16 + quad * 4) = h1;
  if (quad == 0) pl[(size_t)kh * 65536 + (size_t)bh * S_LEN + q0 + m] = l0;
}

// ---------------------------------------------------------------- Proj GEMM (+ fused merge)
// inv table built cooperatively in LDS: coalesced pl loads, 2 rcp/thread.
__global__ __launch_bounds__(256) void proj_gemm(
    const _Float16* __restrict__ W, const float* __restrict__ bias,
    const _Float16* __restrict__ po, const float* __restrict__ pl,
    const float* __restrict__ x, float* __restrict__ out)
{
  __shared__ float Linv[512];                // [n][s_local 64]
  const int tid = threadIdx.x;
  const int lane = tid & 63, wv = tid >> 6;
  const int m = lane & 15, quad = lane >> 4;
  const int mt = blockIdx.x * 4 + wv;  // 0..15
  const int s0 = blockIdx.y * 64;
  const int b = blockIdx.z;
  const int row = mt * 16 + m;

  {
    const int nn = tid >> 5, jj = (tid & 31) * 2;
    size_t base = (size_t)(b * NHEADS + nn) * S_LEN + s0 + jj;
    float a0 = pl[base]     + pl[65536 + base];
    float a1 = pl[base + 1] + pl[65536 + base + 1];
    Linv[nn * 64 + jj]     = 1.f / a0;
    Linv[nn * 64 + jj + 1] = 1.f / a1;
  }
  __syncthreads();

  const _Float16* wrow = W + (size_t)row * C_DIM + quad * 8;
  floatx4 acc0 = {0.f,0.f,0.f,0.f}, acc1 = acc0, acc2 = acc0, acc3 = acc0;
  #pragma unroll
  for (int k0 = 0; k0 < C_DIM; k0 += 32) {
    const int n = k0 >> 5;
    const int d0 = quad * 8;
    half8 bf[4];
    #pragma unroll
    for (int sub = 0; sub < 4; ++sub) {
      size_t idx = (((size_t)(b * NHEADS + n)) * S_LEN + s0 + sub * 16 + m) * HDIM + d0;
      half8 a = *(const half8*)(po + idx);
      half8 c = *(const half8*)(po + 2097152 + idx);
      _Float16 iv = (_Float16)Linv[n * 64 + sub * 16 + m];
      bf[sub] = (a + c) * iv;
    }
    half8 af = *(const half8*)(wrow + k0);
    acc0 = __builtin_amdgcn_mfma_f32_16x16x32_f16(af, bf[0], acc0, 0, 0, 0);
    acc1 = __builtin_amdgcn_mfma_f32_16x16x32_f16(af, bf[1], acc1, 0, 0, 0);
    acc2 = __builtin_amdgcn_mfma_f32_16x16x32_f16(af, bf[2], acc2, 0, 0, 0);
    acc3 = __builtin_amdgcn_mfma_f32_16x16x32_f16(af, bf[3], acc3, 0, 0, 0);
  }
  floatx4 accs[4] = {acc0, acc1, acc2, acc3};
  #pragma unroll
  for (int sub = 0; sub < 4; ++sub) {
    int s = s0 + sub * 16 + m;
    #pragma unroll
    for (int r = 0; r < 4; ++r) {
      int c = mt * 16 + quad * 4 + r;
      size_t idx = ((size_t)b * C_DIM + c) * S_LEN + s;
      out[idx] = x[idx] + accs[sub][r] + bias[c];
    }
  }
}

// ---------------------------------------------------------------- launch
extern "C" void kernel_launch(void* const* d_in, const int* in_sizes, int n_in,
                              void* d_out, int out_size, void* d_ws, size_t ws_size,
                              hipStream_t stream) {
  const float* x        = (const float*)d_in[0];
  const float* gn_gamma = (const float*)d_in[1];
  const float* gn_beta  = (const float*)d_in[2];
  const float* qkv_w    = (const float*)d_in[3];
  const float* qkv_b    = (const float*)d_in[4];
  const float* proj_w   = (const float*)d_in[5];
  const float* proj_b   = (const float*)d_in[6];
  float* out = (float*)d_out;

  const size_t n1 = (size_t)2 * S_LEN * C_DIM;   // 2M elems = 4 MB f16
  char* ws = (char*)d_ws;
  _Float16* qx  = (_Float16*)ws;                 // (B,NH,S,hd)
  _Float16* kx  = qx + n1;                       // (B,NH,S,hd)
  _Float16* vx  = kx + n1;                       // (B,NH,hd,S)
  _Float16* wq  = vx + n1;                       // 768x256 f16
  _Float16* wp  = wq + 768 * 256;                // 256x256 f16
  float*    qbias = (float*)(wp + 256 * 256);    // 768 f32
  float*    pstat = qbias + 768;                 // 64*8*2 f32 = 4 KB
  _Float16* po  = (_Float16*)(pstat + 1024);     // 2 x 2M f16 = 8 MB
  float*    pl  = (float*)(po + 2 * n1);         // 2 x 64K f32 = 512 KB

  prep_stats<<<1539, 256, 0, stream>>>(qkv_w, proj_w, qkv_b, x, wq, wp, qbias, pstat);
  qkv_gn_gemm<<<dim3(6, 64, 2), 256, 0, stream>>>(wq, qbias, x, gn_gamma, gn_beta, pstat, qx, kx, vx);
  attn_kernel<<<dim3(64, 8, 2), 512, 0, stream>>>(qx, kx, vx, po, pl);
  proj_gemm<<<dim3(4, 64, 2), 256, 0, stream>>>(wp, proj_b, po, pl, x, out);
}

// Round 13
// 151.192 us; speedup vs baseline: 1.2656x; 1.0244x over previous
//
#include <hip/hip_runtime.h>
#include <cstddef>

#define S_LEN 4096
#define C_DIM 256
#define NHEADS 8
#define HDIM 32

typedef __attribute__((ext_vector_type(8))) _Float16 half8;
typedef __attribute__((ext_vector_type(4))) _Float16 half4;
typedef __attribute__((ext_vector_type(2))) _Float16 h2t;
typedef __attribute__((ext_vector_type(2))) __fp16 fp16x2;
typedef __attribute__((ext_vector_type(4))) float floatx4;

// scale * log2(e) folded into W_q and bias_q at prep time
#define SC2F ((float)(0.17677669529663687 * 1.4426950408889634))

// ---------------------------------------------------------------- prep + GN partial stats
__global__ __launch_bounds__(256) void prep_stats(
    const float* __restrict__ qkv_w, const float* __restrict__ proj_w,
    const float* __restrict__ qkv_b, const float* __restrict__ x,
    _Float16* __restrict__ wq, _Float16* __restrict__ wp,
    float* __restrict__ qbias, float* __restrict__ pstat)
{
  const int blk = blockIdx.x;
  const int tid = threadIdx.x;
  if (blk < 512) {
    __shared__ float red[2][4];
    const int gb = blk >> 3, e = blk & 7;       // gb = b*32+g
    const int g = gb & 31, b = gb >> 5;
    const float* xb = x + ((size_t)b * C_DIM + g * 8) * S_LEN + e * 4096;
    const float4* x4 = (const float4*)xb;       // 1024 float4
    float sum = 0.f, sumsq = 0.f;
    #pragma unroll
    for (int i = 0; i < 4; ++i) {
      float4 v = x4[tid + i * 256];
      sum += v.x + v.y + v.z + v.w;
      sumsq += v.x * v.x + v.y * v.y + v.z * v.z + v.w * v.w;
    }
    for (int off = 1; off < 64; off <<= 1) {
      sum += __shfl_xor(sum, off, 64);
      sumsq += __shfl_xor(sumsq, off, 64);
    }
    const int wv = tid >> 6, lane = tid & 63;
    if (lane == 0) { red[0][wv] = sum; red[1][wv] = sumsq; }
    __syncthreads();
    if (tid == 0) {
      pstat[(gb * 8 + e) * 2 + 0] = red[0][0] + red[0][1] + red[0][2] + red[0][3];
      pstat[(gb * 8 + e) * 2 + 1] = red[1][0] + red[1][1] + red[1][2] + red[1][3];
    }
  } else {
    int idx = (blk - 512) * 256 + tid;
    if (idx < 768 * 256) {
      float v = qkv_w[idx];
      if (idx < 256 * 256) v *= SC2F;          // q rows
      wq[idx] = (_Float16)v;
    } else if (idx < 768 * 256 + 256 * 256) {
      int i = idx - 768 * 256;
      wp[i] = (_Float16)proj_w[i];
    } else if (idx < 768 * 256 + 256 * 256 + 768) {
      int i = idx - (768 * 256 + 256 * 256);
      float bv = qkv_b[i];
      if (i < 256) bv *= SC2F;
      qbias[i] = bv;
    }
  }
}

// ---------------------------------------------------------------- QKV GEMM + inline GN
__global__ __launch_bounds__(256) void qkv_gn_gemm(
    const _Float16* __restrict__ W, const float* __restrict__ bias,
    const float* __restrict__ x, const float* __restrict__ gamma,
    const float* __restrict__ beta, const float* __restrict__ pstat,
    _Float16* __restrict__ qo, _Float16* __restrict__ ko_,
    _Float16* __restrict__ vo)
{
  __shared__ __align__(16) _Float16 Ld[64 * 264];   // [s][c], stride 264
  const int tid = threadIdx.x;
  const int b = blockIdx.z;
  const int s0 = blockIdx.y * 64;

  {  // ---- inline GN apply: x (c,s) -> Ld[s][c] f16
    const int c0 = (tid & 127) * 2, c1 = c0 + 1;
    const int sh = tid >> 7;                         // s-half 0/1
    const int g = c0 >> 3;
    const int gb = b * 32 + g;
    float s = 0.f, sq = 0.f;
    #pragma unroll
    for (int e = 0; e < 8; ++e) {
      s  += pstat[(gb * 8 + e) * 2 + 0];
      sq += pstat[(gb * 8 + e) * 2 + 1];
    }
    const float mean = s * (1.f / 32768.f);
    const float rstd = rsqrtf(sq * (1.f / 32768.f) - mean * mean + 1e-6f);
    const float ga0 = gamma[c0] * rstd, be0 = beta[c0] - mean * ga0;
    const float ga1 = gamma[c1] * rstd, be1 = beta[c1] - mean * ga1;
    const float4* xa = (const float4*)(x + ((size_t)b * C_DIM + c0) * S_LEN + s0 + sh * 32);
    const float4* xc = (const float4*)(x + ((size_t)b * C_DIM + c1) * S_LEN + s0 + sh * 32);
    #pragma unroll
    for (int j = 0; j < 8; ++j) {
      float4 a = xa[j], c = xc[j];
      int sl = sh * 32 + j * 4;
      *(h2t*)&Ld[(sl + 0) * 264 + c0] = (h2t){ (_Float16)(a.x * ga0 + be0), (_Float16)(c.x * ga1 + be1) };
      *(h2t*)&Ld[(sl + 1) * 264 + c0] = (h2t){ (_Float16)(a.y * ga0 + be0), (_Float16)(c.y * ga1 + be1) };
      *(h2t*)&Ld[(sl + 2) * 264 + c0] = (h2t){ (_Float16)(a.z * ga0 + be0), (_Float16)(c.z * ga1 + be1) };
      *(h2t*)&Ld[(sl + 3) * 264 + c0] = (h2t){ (_Float16)(a.w * ga0 + be0), (_Float16)(c.w * ga1 + be1) };
    }
  }
  __syncthreads();

  const int lane = tid & 63, wv = tid >> 6;
  const int m = lane & 15, quad = lane >> 4;
  const int mtb = blockIdx.x * 8 + wv * 2;      // 2 mt tiles per wave
  const _Float16* wrow0 = W + (size_t)((mtb + 0) * 16 + m) * C_DIM + quad * 8;
  const _Float16* wrow1 = W + (size_t)((mtb + 1) * 16 + m) * C_DIM + quad * 8;
  const _Float16* lp = &Ld[m * 264 + quad * 8];

  floatx4 acc[2][4];
  #pragma unroll
  for (int j = 0; j < 2; ++j)
    #pragma unroll
    for (int s = 0; s < 4; ++s) acc[j][s] = (floatx4){0.f,0.f,0.f,0.f};

  #pragma unroll
  for (int k0 = 0; k0 < C_DIM; k0 += 32) {
    half8 b0 = *(const half8*)(lp + k0);
    half8 b1 = *(const half8*)(lp + 16 * 264 + k0);
    half8 b2 = *(const half8*)(lp + 32 * 264 + k0);
    half8 b3 = *(const half8*)(lp + 48 * 264 + k0);
    half8 a0 = *(const half8*)(wrow0 + k0);
    half8 a1 = *(const half8*)(wrow1 + k0);
    acc[0][0] = __builtin_amdgcn_mfma_f32_16x16x32_f16(a0, b0, acc[0][0], 0, 0, 0);
    acc[0][1] = __builtin_amdgcn_mfma_f32_16x16x32_f16(a0, b1, acc[0][1], 0, 0, 0);
    acc[0][2] = __builtin_amdgcn_mfma_f32_16x16x32_f16(a0, b2, acc[0][2], 0, 0, 0);
    acc[0][3] = __builtin_amdgcn_mfma_f32_16x16x32_f16(a0, b3, acc[0][3], 0, 0, 0);
    acc[1][0] = __builtin_amdgcn_mfma_f32_16x16x32_f16(a1, b0, acc[1][0], 0, 0, 0);
    acc[1][1] = __builtin_amdgcn_mfma_f32_16x16x32_f16(a1, b1, acc[1][1], 0, 0, 0);
    acc[1][2] = __builtin_amdgcn_mfma_f32_16x16x32_f16(a1, b2, acc[1][2], 0, 0, 0);
    acc[1][3] = __builtin_amdgcn_mfma_f32_16x16x32_f16(a1, b3, acc[1][3], 0, 0, 0);
  }

  if (blockIdx.x < 4) {
    // ---- q/k epilogue: coalesced half4 stores
    #pragma unroll
    for (int j = 0; j < 2; ++j) {
      const int ob = (mtb + j) * 16 + quad * 4;
      const float bv0 = bias[ob], bv1 = bias[ob + 1],
                  bv2 = bias[ob + 2], bv3 = bias[ob + 3];
      #pragma unroll
      for (int sub = 0; sub < 4; ++sub) {
        int s = s0 + sub * 16 + m;
        half4 h = { (_Float16)(acc[j][sub][0] + bv0), (_Float16)(acc[j][sub][1] + bv1),
                    (_Float16)(acc[j][sub][2] + bv2), (_Float16)(acc[j][sub][3] + bv3) };
        _Float16* dst = (ob < 256) ? qo : ko_;
        int oo = ob & 255, n = oo >> 5, d0 = oo & 31;
        *(half4*)(dst + (((size_t)b * NHEADS + n) * S_LEN + s) * HDIM + d0) = h;
      }
    }
  } else {
    // ---- v epilogue via LDS: stage [128 ch][64 s] (stride 72), store 16B
    __syncthreads();                          // Ld b-frag reads complete
    _Float16* VLd = Ld;                       // reuse, 128*72*2B = 18.4 KB
    #pragma unroll
    for (int j = 0; j < 2; ++j) {
      const int ob = (mtb + j) * 16 + quad * 4;
      const int lch = (wv * 2 + j) * 16 + quad * 4;   // 0..127
      const float bv0 = bias[ob], bv1 = bias[ob + 1],
                  bv2 = bias[ob + 2], bv3 = bias[ob + 3];
      #pragma unroll
      for (int sub = 0; sub < 4; ++sub) {
        int s = sub * 16 + m;
        VLd[(lch + 0) * 72 + s] = (_Float16)(acc[j][sub][0] + bv0);
        VLd[(lch + 1) * 72 + s] = (_Float16)(acc[j][sub][1] + bv1);
        VLd[(lch + 2) * 72 + s] = (_Float16)(acc[j][sub][2] + bv2);
        VLd[(lch + 3) * 72 + s] = (_Float16)(acc[j][sub][3] + bv3);
      }
    }
    __syncthreads();
    const int lch = tid >> 1, sh = tid & 1;   // half-row per thread (32 halfs)
    const int oo = (blockIdx.x - 4) * 128 + lch;    // 0..255
    const int n = oo >> 5, d = oo & 31;
    _Float16* dst = vo + ((size_t)(b * NHEADS + n) * HDIM + d) * S_LEN + s0 + sh * 32;
    const _Float16* src = VLd + lch * 72 + sh * 32;
    *(half8*)(dst + 0)  = *(const half8*)(src + 0);
    *(half8*)(dst + 8)  = *(const half8*)(src + 8);
    *(half8*)(dst + 16) = *(const half8*)(src + 16);
    *(half8*)(dst + 24) = *(const half8*)(src + 24);
  }
}

// ---------------------------------------------------------------- Attention
// R8 staging/tiles + 32 q-rows/wave: qfA/qfB share every kf/vf read and all
// staging. 512 blocks x 8 waves (2 blocks/CU, all resident). kh split kept.
__global__ __launch_bounds__(512) void attn_kernel(
    const _Float16* __restrict__ q, const _Float16* __restrict__ k,
    const _Float16* __restrict__ v, _Float16* __restrict__ po,
    float* __restrict__ pl)
{
  __shared__ __align__(16) _Float16 Kl[2][64 * 40];  // (kk, d) stride 40
  __shared__ __align__(16) _Float16 Vl[2][32 * 68];  // (d, kk) stride 68
  const int tid = threadIdx.x;
  const int lane = tid & 63, wv = tid >> 6;          // wv 0..7
  const int m = lane & 15, quad = lane >> 4;
  const int n = blockIdx.y, b = blockIdx.z;
  const int qc = blockIdx.x >> 1, kh = blockIdx.x & 1;
  const int q0 = qc * 256 + wv * 32;
  const int bh = b * NHEADS + n;

  const _Float16* qb = q + (size_t)bh * S_LEN * HDIM;
  const _Float16* kb = k + (size_t)bh * S_LEN * HDIM + (size_t)kh * 2048 * HDIM;
  const _Float16* vb = v + (size_t)bh * HDIM * S_LEN + (size_t)kh * 2048;

  // Q B-frags (QK): lane q=m holds d=quad*8+j; two 16-row tiles
  half8 qfA = *(const half8*)(qb + (size_t)(q0 + m) * HDIM + quad * 8);
  half8 qfB = *(const half8*)(qb + (size_t)(q0 + 16 + m) * HDIM + quad * 8);

  // staging: wave wv stages K rows [wv*8,+8), V rows [wv*4,+4); 8B per lane
  const int krow = wv * 8 + (lane >> 3), kc = (lane & 7) * 4;
  const int vrow = wv * 4 + (lane >> 4), vc = (lane & 15) * 4;
  const _Float16* kg = kb + (size_t)krow * HDIM + kc;
  const _Float16* vg = vb + (size_t)vrow * S_LEN + vc;
  const int klds = krow * 40 + kc;
  const int vlds = vrow * 68 + vc;

  int2 kreg = *(const int2*)kg;
  int2 vreg = *(const int2*)vg;
  const _Float16* kgp = kg + 64 * HDIM;
  const _Float16* vgp = vg + 64;

  floatx4 oA0 = {0.f,0.f,0.f,0.f}, oA1 = oA0, oB0 = oA0, oB1 = oA0;
  float lA = 0.f, lB = 0.f;
  const fp16x2 one2 = { (__fp16)1.0f, (__fp16)1.0f };

  #pragma unroll 2
  for (int it = 0; it < 32; ++it) {          // 32 x 64 keys = 2048 (half)
    const int bufi = it & 1;
    *(int2*)(&Kl[bufi][klds]) = kreg;
    *(int2*)(&Vl[bufi][vlds]) = vreg;
    kreg = *(const int2*)kgp; kgp += 64 * HDIM;   // unconditional prefetch
    vreg = *(const int2*)vgp; vgp += 64;
    __syncthreads();
    const _Float16* Kb = Kl[bufi];
    const _Float16* Vb = Vl[bufi];
    #pragma unroll
    for (int t = 0; t < 4; ++t) {
      half8 kf = *(const half8*)(Kb + (t * 16 + m) * 40 + quad * 8);
      half4 vf0 = *(const half4*)(Vb + m * 68 + t * 16 + quad * 4);
      half4 vf1 = *(const half4*)(Vb + (16 + m) * 68 + t * 16 + quad * 4);
      floatx4 z = {0.f,0.f,0.f,0.f};
      floatx4 sA = __builtin_amdgcn_mfma_f32_16x16x32_f16(kf, qfA, z, 0, 0, 0);
      floatx4 sB = __builtin_amdgcn_mfma_f32_16x16x32_f16(kf, qfB, z, 0, 0, 0);
      float eA0 = __builtin_amdgcn_exp2f(sA[0]);
      float eA1 = __builtin_amdgcn_exp2f(sA[1]);
      float eA2 = __builtin_amdgcn_exp2f(sA[2]);
      float eA3 = __builtin_amdgcn_exp2f(sA[3]);
      float eB0 = __builtin_amdgcn_exp2f(sB[0]);
      float eB1 = __builtin_amdgcn_exp2f(sB[1]);
      float eB2 = __builtin_amdgcn_exp2f(sB[2]);
      float eB3 = __builtin_amdgcn_exp2f(sB[3]);
      half4 pA, pB;
      fp16x2 pAlo = __builtin_amdgcn_cvt_pkrtz(eA0, eA1);
      fp16x2 pAhi = __builtin_amdgcn_cvt_pkrtz(eA2, eA3);
      fp16x2 pBlo = __builtin_amdgcn_cvt_pkrtz(eB0, eB1);
      fp16x2 pBhi = __builtin_amdgcn_cvt_pkrtz(eB2, eB3);
      *(fp16x2*)&pA = pAlo; *((fp16x2*)&pA + 1) = pAhi;
      *(fp16x2*)&pB = pBlo; *((fp16x2*)&pB + 1) = pBhi;
      lA = __builtin_amdgcn_fdot2(pAlo, one2, lA, false);
      lA = __builtin_amdgcn_fdot2(pAhi, one2, lA, false);
      lB = __builtin_amdgcn_fdot2(pBlo, one2, lB, false);
      lB = __builtin_amdgcn_fdot2(pBhi, one2, lB, false);
      oA0 = __builtin_amdgcn_mfma_f32_16x16x16f16(vf0, pA, oA0, 0, 0, 0);
      oA1 = __builtin_amdgcn_mfma_f32_16x16x16f16(vf1, pA, oA1, 0, 0, 0);
      oB0 = __builtin_amdgcn_mfma_f32_16x16x16f16(vf0, pB, oB0, 0, 0, 0);
      oB1 = __builtin_amdgcn_mfma_f32_16x16x16f16(vf1, pB, oB1, 0, 0, 0);
    }
  }
  // l split across 4 quads (keys) -> reduce
  lA += __shfl_xor(lA, 16, 64); lA += __shfl_xor(lA, 32, 64);
  lB += __shfl_xor(lB, 16, 64); lB += __shfl_xor(lB, 32, 64);
  // partial store (unnormalized): po[kh][bh][q][d] f16, pl[kh][bh*4096+q]
  _Float16* pobase = po + (size_t)kh * 2097152 + ((size_t)bh * S_LEN) * HDIM;
  {
    _Float16* poh = pobase + (size_t)(q0 + m) * HDIM;
    half4 h0 = { (_Float16)oA0[0], (_Float16)oA0[1], (_Float16)oA0[2], (_Float16)oA0[3] };
    half4 h1 = { (_Float16)oA1[0], (_Float16)oA1[1], (_Float16)oA1[2], (_Float16)oA1[3] };
    *(half4*)(poh + quad * 4) = h0;
    *(half4*)(poh + 16 + quad * 4) = h1;
    if (quad == 0) pl[(size_t)kh * 65536 + (size_t)bh * S_LEN + q0 + m] = lA;
  }
  {
    _Float16* poh = pobase + (size_t)(q0 + 16 + m) * HDIM;
    half4 h0 = { (_Float16)oB0[0], (_Float16)oB0[1], (_Float16)oB0[2], (_Float16)oB0[3] };
    half4 h1 = { (_Float16)oB1[0], (_Float16)oB1[1], (_Float16)oB1[2], (_Float16)oB1[3] };
    *(half4*)(poh + quad * 4) = h0;
    *(half4*)(poh + 16 + quad * 4) = h1;
    if (quad == 0) pl[(size_t)kh * 65536 + (size_t)bh * S_LEN + q0 + 16 + m] = lB;
  }
}

// ---------------------------------------------------------------- Proj GEMM (+ fused merge)
__global__ __launch_bounds__(256) void proj_gemm(
    const _Float16* __restrict__ W, const float* __restrict__ bias,
    const _Float16* __restrict__ po, const float* __restrict__ pl,
    const float* __restrict__ x, float* __restrict__ out)
{
  __shared__ float Linv[512];                // [n][s_local 64]
  const int tid = threadIdx.x;
  const int lane = tid & 63, wv = tid >> 6;
  const int m = lane & 15, quad = lane >> 4;
  const int mt = blockIdx.x * 4 + wv;  // 0..15
  const int s0 = blockIdx.y * 64;
  const int b = blockIdx.z;
  const int row = mt * 16 + m;

  {
    const int nn = tid >> 5, jj = (tid & 31) * 2;
    size_t base = (size_t)(b * NHEADS + nn) * S_LEN + s0 + jj;
    float a0 = pl[base]     + pl[65536 + base];
    float a1 = pl[base + 1] + pl[65536 + base + 1];
    Linv[nn * 64 + jj]     = 1.f / a0;
    Linv[nn * 64 + jj + 1] = 1.f / a1;
  }
  __syncthreads();

  const _Float16* wrow = W + (size_t)row * C_DIM + quad * 8;
  floatx4 acc0 = {0.f,0.f,0.f,0.f}, acc1 = acc0, acc2 = acc0, acc3 = acc0;
  #pragma unroll
  for (int k0 = 0; k0 < C_DIM; k0 += 32) {
    const int n = k0 >> 5;
    const int d0 = quad * 8;
    half8 bf[4];
    #pragma unroll
    for (int sub = 0; sub < 4; ++sub) {
      size_t idx = (((size_t)(b * NHEADS + n)) * S_LEN + s0 + sub * 16 + m) * HDIM + d0;
      half8 a = *(const half8*)(po + idx);
      half8 c = *(const half8*)(po + 2097152 + idx);
      _Float16 iv = (_Float16)Linv[n * 64 + sub * 16 + m];
      bf[sub] = (a + c) * iv;
    }
    half8 af = *(const half8*)(wrow + k0);
    acc0 = __builtin_amdgcn_mfma_f32_16x16x32_f16(af, bf[0], acc0, 0, 0, 0);
    acc1 = __builtin_amdgcn_mfma_f32_16x16x32_f16(af, bf[1], acc1, 0, 0, 0);
    acc2 = __builtin_amdgcn_mfma_f32_16x16x32_f16(af, bf[2], acc2, 0, 0, 0);
    acc3 = __builtin_amdgcn_mfma_f32_16x16x32_f16(af, bf[3], acc3, 0, 0, 0);
  }
  floatx4 accs[4] = {acc0, acc1, acc2, acc3};
  #pragma unroll
  for (int sub = 0; sub < 4; ++sub) {
    int s = s0 + sub * 16 + m;
    #pragma unroll
    for (int r = 0; r < 4; ++r) {
      int c = mt * 16 + quad * 4 + r;
      size_t idx = ((size_t)b * C_DIM + c) * S_LEN + s;
      out[idx] = x[idx] + accs[sub][r] + bias[c];
    }
  }
}

// ---------------------------------------------------------------- launch
extern "C" void kernel_launch(void* const* d_in, const int* in_sizes, int n_in,
                              void* d_out, int out_size, void* d_ws, size_t ws_size,
                              hipStream_t stream) {
  const float* x        = (const float*)d_in[0];
  const float* gn_gamma = (const float*)d_in[1];
  const float* gn_beta  = (const float*)d_in[2];
  const float* qkv_w    = (const float*)d_in[3];
  const float* qkv_b    = (const float*)d_in[4];
  const float* proj_w   = (const float*)d_in[5];
  const float* proj_b   = (const float*)d_in[6];
  float* out = (float*)d_out;

  const size_t n1 = (size_t)2 * S_LEN * C_DIM;   // 2M elems = 4 MB f16
  char* ws = (char*)d_ws;
  _Float16* qx  = (_Float16*)ws;                 // (B,NH,S,hd)
  _Float16* kx  = qx + n1;                       // (B,NH,S,hd)
  _Float16* vx  = kx + n1;                       // (B,NH,hd,S)
  _Float16* wq  = vx + n1;                       // 768x256 f16
  _Float16* wp  = wq + 768 * 256;                // 256x256 f16
  float*    qbias = (float*)(wp + 256 * 256);    // 768 f32
  float*    pstat = qbias + 768;                 // 64*8*2 f32 = 4 KB
  _Float16* po  = (_Float16*)(pstat + 1024);     // 2 x 2M f16 = 8 MB
  float*    pl  = (float*)(po + 2 * n1);         // 2 x 64K f32 = 512 KB

  prep_stats<<<1539, 256, 0, stream>>>(qkv_w, proj_w, qkv_b, x, wq, wp, qbias, pstat);
  qkv_gn_gemm<<<dim3(6, 64, 2), 256, 0, stream>>>(wq, qbias, x, gn_gamma, gn_beta, pstat, qx, kx, vx);
  attn_kernel<<<dim3(32, 8, 2), 512, 0, stream>>>(qx, kx, vx, po, pl);
  proj_gemm<<<dim3(4, 64, 2), 256, 0, stream>>>(wp, proj_b, po, pl, x, out);
}